// Round 1
// baseline (532.455 us; speedup 1.0000x reference)
//
#include <hip/hip_runtime.h>

// Problem constants
#define DIMX 256
#define HIDX 128
#define NMX  32768   // N*M tokens per batch
#define TBX  128     // tokens per workgroup

typedef short s16x8 __attribute__((ext_vector_type(8)));  // 8 bf16 in 4 VGPRs
typedef float f32x4 __attribute__((ext_vector_type(4)));

// ws layout (bytes): packed bf16 A-fragments per matrix, then fp32 Wkv temp
#define OFF_WQN   (0u)        // -Wq  (K=256,E=256) 128KB
#define OFF_WK    (131072u)   //  Wk                128KB
#define OFF_WKV   (262144u)   //  Wk@Wv             128KB
#define OFF_W1    (393216u)   //  W1  (K=256,E=128)  64KB
#define OFF_W2    (458752u)   //  W2  (K=128,E=256)  64KB
#define OFF_WO    (524288u)   //  Wo                128KB
#define OFF_KVF32 (655360u)   //  fp32 Wkv temp     256KB

__device__ __forceinline__ ushort f2bf(float f) {
  uint u = __builtin_bit_cast(uint, f);
  return (ushort)((u + 0x7FFFu + ((u >> 16) & 1u)) >> 16);  // RNE
}

// K0: Wkv = Wk @ Wv in fp32 (256x256x256, trivial)
__global__ void wkv_kernel(const float* __restrict__ Wk, const float* __restrict__ Wv,
                           float* __restrict__ outw) {
  const int e = threadIdx.x, d = blockIdx.x;
  float acc = 0.f;
  #pragma unroll 8
  for (int m = 0; m < DIMX; ++m) acc += Wk[d * DIMX + m] * Wv[m * DIMX + e];
  outw[d * DIMX + e] = acc;
}

// K1: pack all weights into MFMA A-fragment order, bf16.
// A-frag for W(K x E) used as A = W^T: value[lane][j] = W[ks*32+(lane>>4)*8+j][r*16+(lane&15)]
// frag id = ks*(E/16)+r, stored at off + (frag*64+lane)*16 bytes.
__global__ void pack_kernel(const float* __restrict__ Wq, const float* __restrict__ Wk,
                            const float* __restrict__ Wkvf, const float* __restrict__ W1,
                            const float* __restrict__ W2, const float* __restrict__ Wo,
                            ushort* __restrict__ wsout) {
  const int fid = blockIdx.x, lane = threadIdx.x;  // 640 blocks x 64 threads
  const float* src; int Eout = 256; float sgn = 1.f; uint off; int local;
  if (fid < 128)      { src = Wq;   sgn = -1.f; off = OFF_WQN; local = fid;       }
  else if (fid < 256) { src = Wk;   off = OFF_WK;  local = fid - 128;             }
  else if (fid < 384) { src = Wkvf; off = OFF_WKV; local = fid - 256;             }
  else if (fid < 448) { src = W1;   Eout = 128; off = OFF_W1; local = fid - 384;  }
  else if (fid < 512) { src = W2;   off = OFF_W2;  local = fid - 448;             }
  else                { src = Wo;   off = OFF_WO;  local = fid - 512;             }
  const int R  = Eout >> 4;
  const int ks = local / R, r = local - ks * R;
  const int e  = r * 16 + (lane & 15);
  const int k0 = ks * 32 + (lane >> 4) * 8;
  union { uint4 u4; ushort us[8]; } o;
  #pragma unroll
  for (int j = 0; j < 8; ++j) o.us[j] = f2bf(sgn * src[(k0 + j) * Eout + e]);
  *(uint4*)((char*)wsout + off + (((uint)local * 64u + (uint)lane) * 16u)) = o.u4;
}

// Main fused kernel: per WG = 128 tokens of one batch.
// All GEMMs in transposed form C[e][t] = W^T * data; data tile in LDS as [d][t] bf16
// with XOR swizzle; tokens are wave-private columns -> no barriers after k staging.
__global__ __launch_bounds__(512, 2) void fused_main(
    const float* __restrict__ q, const float* __restrict__ kin,
    const float* __restrict__ pos, const int* __restrict__ mask,
    const float* __restrict__ b1, const float* __restrict__ b2,
    const float* __restrict__ bo, const ushort* __restrict__ wfr,
    float* __restrict__ out)
{
  __shared__ ushort tile[DIMX * TBX];  // 64KB, reused for q, k, attn, h, x
  char* tb = (char*)tile;
  const char* wb = (const char*)wfr;

  const int tid = threadIdx.x;
  const int w = tid >> 6, l = tid & 63;
  const int c = l & 15, g = l >> 4;
  const int b  = blockIdx.x >> 8;            // 256 tile-blocks per batch
  const int t0 = (blockIdx.x & 255) * TBX;
  const int tw = w << 4;                     // wave's 16-column slice
  const int tg = t0 + tw + c;                // this lane's token (within batch)

  // swizzled LDS byte offset for element (d, t), row pitch 256B
  auto ldsb = [&](int d, int t) -> int {
    int byte = d * (TBX * 2) + (t << 1);
    return byte ^ (((d >> 3) & 3) << 5);
  };

  // coalesced stage of one (q or k) [256][128] fp32 plane slice -> bf16 LDS tile
  auto stage = [&](const float* __restrict__ src) {
    const float* base = src + (size_t)b * DIMX * NMX + t0;
    #pragma unroll 4
    for (int it = 0; it < 32; ++it) {
      const int d = w + (it << 3);
      const float2 v = *(const float2*)(base + (size_t)d * NMX + (l << 1));
      const uint p = (uint)f2bf(v.x) | ((uint)f2bf(v.y) << 16);
      int byte = d * (TBX * 2) + (l << 2);
      byte ^= ((d >> 3) & 3) << 5;
      *(uint*)(tb + byte) = p;
    }
  };

  // B-fragment gather: col = tw+c, k = ks*32 + g*8 + j   (conflict-free via swizzle)
  auto gatherB = [&](int ks) -> s16x8 {
    union { s16x8 v; ushort u[8]; } f;
    #pragma unroll
    for (int j = 0; j < 8; ++j) {
      const int d = ks * 32 + g * 8 + j;
      f.u[j] = *(const ushort*)(tb + ldsb(d, tw + c));
    }
    return f.v;
  };

  // A-fragment (weights) from packed global, 16B/lane
  auto ldA = [&](uint moff, int fi) -> s16x8 {
    return *(const s16x8*)(wb + moff + (((uint)fi * 64u + (uint)l) * 16u));
  };

  // intermediate scalar store into tile at (row e, this lane's column)
  auto stW = [&](int e, float val) {
    *(ushort*)(tb + ldsb(e, tw + c)) = f2bf(val);
  };

  f32x4 acc_a[16], acc_v[16];
  #pragma unroll
  for (int r = 0; r < 16; ++r) { acc_a[r] = f32x4{0.f,0.f,0.f,0.f}; acc_v[r] = f32x4{0.f,0.f,0.f,0.f}; }

  // ---- stage q; G1: acc_a = (-Wq)^T q  = -qh ----
  stage(q);
  __syncthreads();
  #pragma unroll 1
  for (int ks = 0; ks < 8; ++ks) {
    const s16x8 bf = gatherB(ks);
    #pragma unroll
    for (int r = 0; r < 16; ++r)
      acc_a[r] = __builtin_amdgcn_mfma_f32_16x16x32_bf16(ldA(OFF_WQN, ks*16 + r), bf, acc_a[r], 0, 0, 0);
  }
  __syncthreads();

  // ---- stage k; G2: acc_a += Wk^T k (=kh-qh);  acc_v = (WkWv)^T k (=v) ----
  stage(kin);
  __syncthreads();
  #pragma unroll 1
  for (int ks = 0; ks < 8; ++ks) {
    const s16x8 bf = gatherB(ks);
    #pragma unroll
    for (int r = 0; r < 16; ++r) {
      acc_a[r] = __builtin_amdgcn_mfma_f32_16x16x32_bf16(ldA(OFF_WK,  ks*16 + r), bf, acc_a[r], 0, 0, 0);
      acc_v[r] = __builtin_amdgcn_mfma_f32_16x16x32_bf16(ldA(OFF_WKV, ks*16 + r), bf, acc_v[r], 0, 0, 0);
    }
  }

  // ---- attn_pre = acc_a + pos -> bf16 tile (columns are wave-private: no barrier) ----
  const float* posb = pos + ((size_t)b * NMX + tg) * DIMX + (g << 2);
  #pragma unroll
  for (int r = 0; r < 16; ++r) {
    const f32x4 p4 = *(const f32x4*)(posb + (r << 4));
    #pragma unroll
    for (int i = 0; i < 4; ++i)
      stW(r * 16 + g * 4 + i, acc_a[r][i] + p4[i]);
  }

  // ---- G3: h = relu(W1^T attn + b1) -> tile rows 0..127 ----
  f32x4 acc_h[8];
  #pragma unroll
  for (int r = 0; r < 8; ++r) acc_h[r] = f32x4{0.f,0.f,0.f,0.f};
  #pragma unroll 1
  for (int ks = 0; ks < 8; ++ks) {
    const s16x8 bf = gatherB(ks);
    #pragma unroll
    for (int r = 0; r < 8; ++r)
      acc_h[r] = __builtin_amdgcn_mfma_f32_16x16x32_bf16(ldA(OFF_W1, ks*8 + r), bf, acc_h[r], 0, 0, 0);
  }
  #pragma unroll
  for (int r = 0; r < 8; ++r) {
    const f32x4 bb = *(const f32x4*)(b1 + r * 16 + g * 4);
    #pragma unroll
    for (int i = 0; i < 4; ++i)
      stW(r * 16 + g * 4 + i, fmaxf(acc_h[r][i] + bb[i], 0.f));
  }

  // ---- G4: a2 = W2^T h + b2; mask; sigmoid; x = (v+pos)*sig -> bf16 tile ----
  f32x4 acc_s[16];
  #pragma unroll
  for (int r = 0; r < 16; ++r) acc_s[r] = f32x4{0.f,0.f,0.f,0.f};
  #pragma unroll 1
  for (int ks = 0; ks < 4; ++ks) {
    const s16x8 bf = gatherB(ks);  // reads h rows 0..127
    #pragma unroll
    for (int r = 0; r < 16; ++r)
      acc_s[r] = __builtin_amdgcn_mfma_f32_16x16x32_bf16(ldA(OFF_W2, ks*16 + r), bf, acc_s[r], 0, 0, 0);
  }
  const int mk = mask[b * NMX + tg];
  #pragma unroll
  for (int r = 0; r < 16; ++r) {
    const f32x4 p4  = *(const f32x4*)(posb + (r << 4));
    const f32x4 b2v = *(const f32x4*)(b2 + r * 16 + g * 4);
    #pragma unroll
    for (int i = 0; i < 4; ++i) {
      float sv = acc_s[r][i] + b2v[i];
      if (mk == 0) sv = -1e9f;
      const float sig = 1.f / (1.f + __expf(-sv));
      stW(r * 16 + g * 4 + i, (acc_v[r][i] + p4[i]) * sig);
    }
  }

  // ---- G5: out = Wo^T x + bo, store to (B,D,N,M) ----
  f32x4 acc_o[16];
  #pragma unroll
  for (int r = 0; r < 16; ++r) acc_o[r] = f32x4{0.f,0.f,0.f,0.f};
  #pragma unroll 1
  for (int ks = 0; ks < 8; ++ks) {
    const s16x8 bf = gatherB(ks);
    #pragma unroll
    for (int r = 0; r < 16; ++r)
      acc_o[r] = __builtin_amdgcn_mfma_f32_16x16x32_bf16(ldA(OFF_WO, ks*16 + r), bf, acc_o[r], 0, 0, 0);
  }
  float* ob = out + (size_t)b * DIMX * NMX + tg;
  #pragma unroll
  for (int r = 0; r < 16; ++r) {
    const f32x4 bov = *(const f32x4*)(bo + r * 16 + g * 4);
    #pragma unroll
    for (int i = 0; i < 4; ++i)
      ob[(size_t)(r * 16 + g * 4 + i) * NMX] = acc_o[r][i] + bov[i];
  }
}

extern "C" void kernel_launch(void* const* d_in, const int* in_sizes, int n_in,
                              void* d_out, int out_size, void* d_ws, size_t ws_size,
                              hipStream_t stream) {
  (void)in_sizes; (void)n_in; (void)out_size; (void)ws_size;
  const float* q   = (const float*)d_in[0];
  const float* k   = (const float*)d_in[1];
  const float* pos = (const float*)d_in[2];
  const int*   msk = (const int*)d_in[3];
  const float* Wq  = (const float*)d_in[4];
  const float* Wk  = (const float*)d_in[5];
  const float* Wv  = (const float*)d_in[6];
  const float* W1  = (const float*)d_in[7];
  const float* b1  = (const float*)d_in[8];
  const float* W2  = (const float*)d_in[9];
  const float* b2  = (const float*)d_in[10];
  const float* Wo  = (const float*)d_in[11];
  const float* bo  = (const float*)d_in[12];
  float* out = (float*)d_out;
  char* ws = (char*)d_ws;
  float*  wkvf = (float*)(ws + OFF_KVF32);
  ushort* wfr  = (ushort*)ws;

  wkv_kernel<<<dim3(256), dim3(256), 0, stream>>>(Wk, Wv, wkvf);
  pack_kernel<<<dim3(640), dim3(64), 0, stream>>>(Wq, Wk, wkvf, W1, W2, Wo, wfr);
  fused_main<<<dim3(1024), dim3(512), 0, stream>>>(q, k, pos, msk, b1, b2, bo, wfr, out);
}

// Round 2
// 206.060 us; speedup vs baseline: 2.5840x; 2.5840x over previous
//
#include <hip/hip_runtime.h>

// Problem constants
#define DIMX 256
#define NMX  32768   // N*M tokens per batch
#define TB   64      // tokens per workgroup

typedef short s16x8 __attribute__((ext_vector_type(8)));  // 8 bf16 in 4 VGPRs
typedef float f32x4 __attribute__((ext_vector_type(4)));

// ws layout (bytes): packed bf16 A-fragments per matrix, then fp32 Wkv temp
#define OFF_WQN   (0u)        // -Wq  (K=256,E=256) 128KB
#define OFF_WK    (131072u)   //  Wk                128KB
#define OFF_WKV   (262144u)   //  Wk@Wv             128KB
#define OFF_W1    (393216u)   //  W1  (K=256,E=128)  64KB
#define OFF_W2    (458752u)   //  W2  (K=128,E=256)  64KB
#define OFF_WO    (524288u)   //  Wo                128KB
#define OFF_KVF32 (655360u)   //  fp32 Wkv temp     256KB

__device__ __forceinline__ ushort f2bf(float f) {
  uint u = __builtin_bit_cast(uint, f);
  return (ushort)((u + 0x7FFFu + ((u >> 16) & 1u)) >> 16);  // RNE
}

// K0: Wkv = Wk @ Wv in fp32 (256x256x256, trivial)
__global__ void wkv_kernel(const float* __restrict__ Wk, const float* __restrict__ Wv,
                           float* __restrict__ outw) {
  const int e = threadIdx.x, d = blockIdx.x;
  float acc = 0.f;
  #pragma unroll 8
  for (int m = 0; m < DIMX; ++m) acc += Wk[d * DIMX + m] * Wv[m * DIMX + e];
  outw[d * DIMX + e] = acc;
}

// K1: pack all weights into MFMA A-fragment order, bf16.
// A-frag for W(K x E) used as A = W^T: value[lane][j] = W[ks*32+(lane>>4)*8+j][r*16+(lane&15)]
// frag id = ks*(E/16)+r, stored at off + (frag*64+lane)*16 bytes.
__global__ void pack_kernel(const float* __restrict__ Wq, const float* __restrict__ Wk,
                            const float* __restrict__ Wkvf, const float* __restrict__ W1,
                            const float* __restrict__ W2, const float* __restrict__ Wo,
                            ushort* __restrict__ wsout) {
  const int fid = blockIdx.x, lane = threadIdx.x;  // 640 blocks x 64 threads
  const float* src; int Eout = 256; float sgn = 1.f; uint off; int local;
  if (fid < 128)      { src = Wq;   sgn = -1.f; off = OFF_WQN; local = fid;       }
  else if (fid < 256) { src = Wk;   off = OFF_WK;  local = fid - 128;             }
  else if (fid < 384) { src = Wkvf; off = OFF_WKV; local = fid - 256;             }
  else if (fid < 448) { src = W1;   Eout = 128; off = OFF_W1; local = fid - 384;  }
  else if (fid < 512) { src = W2;   off = OFF_W2;  local = fid - 448;             }
  else                { src = Wo;   off = OFF_WO;  local = fid - 512;             }
  const int R  = Eout >> 4;
  const int ks = local / R, r = local - ks * R;
  const int e  = r * 16 + (lane & 15);
  const int k0 = ks * 32 + (lane >> 4) * 8;
  union { uint4 u4; ushort us[8]; } o;
  #pragma unroll
  for (int j = 0; j < 8; ++j) o.us[j] = f2bf(sgn * src[(k0 + j) * Eout + e]);
  *(uint4*)((char*)wsout + off + (((uint)local * 64u + (uint)lane) * 16u)) = o.u4;
}

// Main fused kernel. WG = 64 tokens of one batch, 8 waves.
// Wave w owns output rows [w*32, w*32+32) (rows [w*16,w*16+16) for the 128-wide
// hidden stage) for ALL 64 tokens. Data tiles live in LDS transposed [t][d] bf16
// (row pitch 512B) with XOR swizzle byte ^= (t&7)<<4 so a B-fragment is one
// ds_read_b128. Two 32KB buffers -> 2 blocks/CU, 16 waves/CU.
#define MFMA16(A,B,C) __builtin_amdgcn_mfma_f32_16x16x32_bf16(A, B, C, 0, 0, 0)

__global__ __launch_bounds__(512, 4) void fused_main(
    const float* __restrict__ q, const float* __restrict__ kin,
    const float* __restrict__ pos, const int* __restrict__ mask,
    const float* __restrict__ b1, const float* __restrict__ b2,
    const float* __restrict__ bo, const ushort* __restrict__ wfr,
    float* __restrict__ out)
{
  __shared__ __align__(1024) ushort bufA[TB * DIMX];  // 32KB: q -> attn -> x
  __shared__ __align__(1024) ushort bufB[TB * DIMX];  // 32KB: k -> h
  const char* wb = (const char*)wfr;

  const int tid = threadIdx.x;
  const int w = tid >> 6, l = tid & 63;
  const int c = l & 15, g = l >> 4;
  const int b  = blockIdx.x >> 9;           // 512 token-blocks per batch
  const int t0 = (blockIdx.x & 511) * TB;

  // B-fragment read: lane supplies B[k = ks*32 + g*8 + j][t = tf*16 + c]
  auto ldB = [&](const ushort* buf, int ks, int tf) -> s16x8 {
    const int t = (tf << 4) + c;
    const int col = (ks << 6) + (g << 4);   // byte offset within row
    return *(const s16x8*)((const char*)buf + t * 512 + (col ^ ((t & 7) << 4)));
  };
  // A-fragment (weights) from packed global, 16B/lane
  auto ldA = [&](uint moff, int fi) -> s16x8 {
    return *(const s16x8*)(wb + moff + (((uint)fi << 6) | (uint)l) * 16u);
  };
  // write 4 consecutive-e bf16 values (packed lo,hi) at (e0, t)
  auto stRow4 = [&](ushort* buf, int e0, int t, uint lo, uint hi) {
    const int byte = t * 512 + (((uint)(e0 * 2)) ^ ((t & 7) << 4));
    *(uint2*)((char*)buf + byte) = uint2{lo, hi};
  };

  // ---- stage q -> bufA, k -> bufB (transposed, bf16, swizzled) ----
  {
    const size_t pbase = (size_t)b * DIMX * NMX + t0 + l;
    #pragma unroll 4
    for (int dd = 0; dd < 32; dd += 2) {
      const int d = (w << 5) + dd;
      const float q0 = q[pbase + (size_t)d * NMX];
      const float q1 = q[pbase + (size_t)(d + 1) * NMX];
      const float k0 = kin[pbase + (size_t)d * NMX];
      const float k1 = kin[pbase + (size_t)(d + 1) * NMX];
      const int byte = l * 512 + ((d * 2) ^ ((l & 7) << 4));
      *(uint*)((char*)bufA + byte) = (uint)f2bf(q0) | ((uint)f2bf(q1) << 16);
      *(uint*)((char*)bufB + byte) = (uint)f2bf(k0) | ((uint)f2bf(k1) << 16);
    }
  }
  __syncthreads();

  // ---- G2b: v = Wkv^T k  (then pack to bf16, freeing the f32 accs) ----
  f32x4 av[2][4];
  #pragma unroll
  for (int ef = 0; ef < 2; ++ef)
    #pragma unroll
    for (int tf = 0; tf < 4; ++tf) av[ef][tf] = f32x4{0.f, 0.f, 0.f, 0.f};
  #pragma unroll 2
  for (int ks = 0; ks < 8; ++ks) {
    const s16x8 a0 = ldA(OFF_WKV, (ks << 4) + (w << 1));
    const s16x8 a1 = ldA(OFF_WKV, (ks << 4) + (w << 1) + 1);
    #pragma unroll
    for (int tf = 0; tf < 4; ++tf) {
      const s16x8 bf = ldB(bufB, ks, tf);
      av[0][tf] = MFMA16(a0, bf, av[0][tf]);
      av[1][tf] = MFMA16(a1, bf, av[1][tf]);
    }
  }
  uint vbf[2][4][2];
  #pragma unroll
  for (int ef = 0; ef < 2; ++ef)
    #pragma unroll
    for (int tf = 0; tf < 4; ++tf)
      #pragma unroll
      for (int p = 0; p < 2; ++p)
        vbf[ef][tf][p] = (uint)f2bf(av[ef][tf][2 * p]) |
                         ((uint)f2bf(av[ef][tf][2 * p + 1]) << 16);

  // ---- G1 + G2a: attn_pre = Wk^T k - Wq^T q ----
  f32x4 aa[2][4];
  #pragma unroll
  for (int ef = 0; ef < 2; ++ef)
    #pragma unroll
    for (int tf = 0; tf < 4; ++tf) aa[ef][tf] = f32x4{0.f, 0.f, 0.f, 0.f};
  #pragma unroll 2
  for (int ks = 0; ks < 8; ++ks) {
    const s16x8 a0 = ldA(OFF_WQN, (ks << 4) + (w << 1));
    const s16x8 a1 = ldA(OFF_WQN, (ks << 4) + (w << 1) + 1);
    #pragma unroll
    for (int tf = 0; tf < 4; ++tf) {
      const s16x8 bf = ldB(bufA, ks, tf);
      aa[0][tf] = MFMA16(a0, bf, aa[0][tf]);
      aa[1][tf] = MFMA16(a1, bf, aa[1][tf]);
    }
  }
  #pragma unroll 2
  for (int ks = 0; ks < 8; ++ks) {
    const s16x8 a0 = ldA(OFF_WK, (ks << 4) + (w << 1));
    const s16x8 a1 = ldA(OFF_WK, (ks << 4) + (w << 1) + 1);
    #pragma unroll
    for (int tf = 0; tf < 4; ++tf) {
      const s16x8 bf = ldB(bufB, ks, tf);
      aa[0][tf] = MFMA16(a0, bf, aa[0][tf]);
      aa[1][tf] = MFMA16(a1, bf, aa[1][tf]);
    }
  }
  __syncthreads();  // everyone done reading q (bufA) and k (bufB)

  // ---- attn = attn_pre + pos -> bf16 into bufA rows [w*32, w*32+32) ----
  #pragma unroll
  for (int tf = 0; tf < 4; ++tf) {
    const int t = (tf << 4) + c;
    const float* pp = pos + ((size_t)b * NMX + t0 + t) * DIMX;
    #pragma unroll
    for (int ef = 0; ef < 2; ++ef) {
      const int e0 = (w << 5) + (ef << 4) + (g << 2);
      const f32x4 p4 = *(const f32x4*)(pp + e0);
      const uint lo = (uint)f2bf(aa[ef][tf][0] + p4[0]) |
                      ((uint)f2bf(aa[ef][tf][1] + p4[1]) << 16);
      const uint hi = (uint)f2bf(aa[ef][tf][2] + p4[2]) |
                      ((uint)f2bf(aa[ef][tf][3] + p4[3]) << 16);
      stRow4(bufA, e0, t, lo, hi);
    }
  }
  __syncthreads();  // attn tile complete

  // ---- G3: h = relu(W1^T attn + b1) -> bufB cols [w*16, w*16+16) ----
  f32x4 ah[4];
  #pragma unroll
  for (int tf = 0; tf < 4; ++tf) ah[tf] = f32x4{0.f, 0.f, 0.f, 0.f};
  #pragma unroll 2
  for (int ks = 0; ks < 8; ++ks) {
    const s16x8 a0 = ldA(OFF_W1, (ks << 3) + w);
    #pragma unroll
    for (int tf = 0; tf < 4; ++tf) {
      const s16x8 bf = ldB(bufA, ks, tf);
      ah[tf] = MFMA16(a0, bf, ah[tf]);
    }
  }
  {
    const int e0 = (w << 4) + (g << 2);
    const f32x4 b1v = *(const f32x4*)(b1 + e0);
    #pragma unroll
    for (int tf = 0; tf < 4; ++tf) {
      const int t = (tf << 4) + c;
      const uint lo = (uint)f2bf(fmaxf(ah[tf][0] + b1v[0], 0.f)) |
                      ((uint)f2bf(fmaxf(ah[tf][1] + b1v[1], 0.f)) << 16);
      const uint hi = (uint)f2bf(fmaxf(ah[tf][2] + b1v[2], 0.f)) |
                      ((uint)f2bf(fmaxf(ah[tf][3] + b1v[3], 0.f)) << 16);
      stRow4(bufB, e0, t, lo, hi);
    }
  }
  __syncthreads();  // h tile complete

  // ---- G4: a2 = W2^T h + b2; mask; sigmoid; x = (v+pos)*sig -> bufA ----
  f32x4 as[2][4];
  #pragma unroll
  for (int ef = 0; ef < 2; ++ef)
    #pragma unroll
    for (int tf = 0; tf < 4; ++tf) as[ef][tf] = f32x4{0.f, 0.f, 0.f, 0.f};
  #pragma unroll
  for (int ks = 0; ks < 4; ++ks) {
    const s16x8 a0 = ldA(OFF_W2, (ks << 4) + (w << 1));
    const s16x8 a1 = ldA(OFF_W2, (ks << 4) + (w << 1) + 1);
    #pragma unroll
    for (int tf = 0; tf < 4; ++tf) {
      const s16x8 bf = ldB(bufB, ks, tf);
      as[0][tf] = MFMA16(a0, bf, as[0][tf]);
      as[1][tf] = MFMA16(a1, bf, as[1][tf]);
    }
  }
  #pragma unroll
  for (int tf = 0; tf < 4; ++tf) {
    const int t = (tf << 4) + c;
    const int mk = mask[(size_t)b * NMX + t0 + t];
    const float* pp = pos + ((size_t)b * NMX + t0 + t) * DIMX;
    #pragma unroll
    for (int ef = 0; ef < 2; ++ef) {
      const int e0 = (w << 5) + (ef << 4) + (g << 2);
      const f32x4 p4  = *(const f32x4*)(pp + e0);
      const f32x4 b2v = *(const f32x4*)(b2 + e0);
      float xv[4];
      #pragma unroll
      for (int i = 0; i < 4; ++i) {
        float sv = as[ef][tf][i] + b2v[i];
        if (mk == 0) sv = -1e9f;
        const float sig = 1.f / (1.f + __expf(-sv));
        const uint pv = vbf[ef][tf][i >> 1];
        const float vv = (i & 1) ? __builtin_bit_cast(float, pv & 0xffff0000u)
                                 : __builtin_bit_cast(float, pv << 16);
        xv[i] = (vv + p4[i]) * sig;
      }
      const uint lo = (uint)f2bf(xv[0]) | ((uint)f2bf(xv[1]) << 16);
      const uint hi = (uint)f2bf(xv[2]) | ((uint)f2bf(xv[3]) << 16);
      stRow4(bufA, e0, t, lo, hi);
    }
  }
  __syncthreads();  // x tile complete

  // ---- G5: out = Wo^T x + bo -> (B, D, N, M) ----
  f32x4 ao[2][4];
  #pragma unroll
  for (int ef = 0; ef < 2; ++ef)
    #pragma unroll
    for (int tf = 0; tf < 4; ++tf) ao[ef][tf] = f32x4{0.f, 0.f, 0.f, 0.f};
  #pragma unroll 2
  for (int ks = 0; ks < 8; ++ks) {
    const s16x8 a0 = ldA(OFF_WO, (ks << 4) + (w << 1));
    const s16x8 a1 = ldA(OFF_WO, (ks << 4) + (w << 1) + 1);
    #pragma unroll
    for (int tf = 0; tf < 4; ++tf) {
      const s16x8 bf = ldB(bufA, ks, tf);
      ao[0][tf] = MFMA16(a0, bf, ao[0][tf]);
      ao[1][tf] = MFMA16(a1, bf, ao[1][tf]);
    }
  }
  #pragma unroll
  for (int ef = 0; ef < 2; ++ef) {
    const int e0 = (w << 5) + (ef << 4) + (g << 2);
    const f32x4 bov = *(const f32x4*)(bo + e0);
    #pragma unroll
    for (int i = 0; i < 4; ++i) {
      float* ob = out + ((size_t)b * DIMX + e0 + i) * NMX + t0 + c;
      #pragma unroll
      for (int tf = 0; tf < 4; ++tf)
        ob[tf << 4] = ao[ef][tf][i] + bov[i];
    }
  }
}

extern "C" void kernel_launch(void* const* d_in, const int* in_sizes, int n_in,
                              void* d_out, int out_size, void* d_ws, size_t ws_size,
                              hipStream_t stream) {
  (void)in_sizes; (void)n_in; (void)out_size; (void)ws_size;
  const float* q   = (const float*)d_in[0];
  const float* k   = (const float*)d_in[1];
  const float* pos = (const float*)d_in[2];
  const int*   msk = (const int*)d_in[3];
  const float* Wq  = (const float*)d_in[4];
  const float* Wk  = (const float*)d_in[5];
  const float* Wv  = (const float*)d_in[6];
  const float* W1  = (const float*)d_in[7];
  const float* b1  = (const float*)d_in[8];
  const float* W2  = (const float*)d_in[9];
  const float* b2  = (const float*)d_in[10];
  const float* Wo  = (const float*)d_in[11];
  const float* bo  = (const float*)d_in[12];
  float* out = (float*)d_out;
  char* ws = (char*)d_ws;
  float*  wkvf = (float*)(ws + OFF_KVF32);
  ushort* wfr  = (ushort*)ws;

  wkv_kernel<<<dim3(256), dim3(256), 0, stream>>>(Wk, Wv, wkvf);
  pack_kernel<<<dim3(640), dim3(64), 0, stream>>>(Wq, Wk, wkvf, W1, W2, Wo, wfr);
  fused_main<<<dim3(2048), dim3(512), 0, stream>>>(q, k, pos, msk, b1, b2, bo, wfr, out);
}